// Round 5
// baseline (4332.098 us; speedup 1.0000x reference)
//
#include <hip/hip_runtime.h>
#include <math.h>

#define NB 16
#define NR 100
#define NV 50000
#define ND 1024
#define NT 20
#define VP1 50001
#define VP1R 50004     // padded row stride (float4-aligned rows)
#define VTT 50101
#define RP1 101
#define NEGF (-1e10f)
#define LSE_TILES 49   // ceil(50001/1024)
#define NSLICE 13      // 13*4096 = 53248 >= 50101
#define NBLK3 (NB*NSLICE)      // 208
#define MERGE_N (NBLK3*16)     // 3328

struct P {
  const float* embed; const float* Wx; const float* Wh; const float* Wc;
  const float* Wl; const float* Wd; const float* rnn0; const float* det0;
  const float* h0; const float* pool; const float* ppls; const float* pnt;
  float* logits;   // [16][VP1R]
  float* lse;      // [16]
  float* dlp;      // [16][101]
  float* rnnT;     // [1024][16]
  float* hst;      // [16][1024]
  float* hhgT;     // [1024][16]
  float* xtT;      // [1024][16]
  float* ctxT;     // [1024][16]
  float* mask0; float* mask1;       // [16][101] ping-pong
  int* bs0; int* bs1;               // [20][16] ping-pong
  float* blp0; float* blp1;         // [20][16] ping-pong
  float* lpsum;    // [16]
  float* pkv; unsigned* pkf;        // [MERGE_N]
  float* part;     // [32][16][1024]
  float* blkM; float* blkS;         // [16*49]
};

__device__ __forceinline__ bool better(float av, unsigned af, float bv, unsigned bf){
  return (av > bv) || (av == bv && af < bf);
}
__device__ __forceinline__ void lsecomb(float& m, float& s, float m2, float s2){
  float M = fmaxf(m, m2);
  if (M == -INFINITY){ m = M; s = 0.f; return; }
  s = s*expf(m - M) + s2*expf(m2 - M);
  m = M;
}

// ---------------- K0: init ----------------
__global__ __launch_bounds__(256) void k0_init(P p){
  int i = blockIdx.x*256 + threadIdx.x;
  int n = gridDim.x*256;
  for (int o=i; o<NB*ND; o+=n){ int b=o>>10, k=o&1023; p.rnnT[k*NB+b] = p.rnn0[o]; }
  for (int o=i; o<NT*NB; o+=n){ p.bs0[o]=0; p.bs1[o]=0; p.blp0[o]=0.f; p.blp1[o]=0.f; }
  for (int o=i; o<NB; o+=n) p.lpsum[o]=0.f;
}

// ---------------- K1: logits = rnn_out @ Wl ----------------
// 1563 blocks x 256 thr: 32 j-cols/block, 8-way k split (128 k each).
// Small LDS (17 KB) + big grid -> ~6 blocks/CU, latency hidden by TLP.
__global__ __launch_bounds__(256) void k1_logits(const float* __restrict__ Wl,
    const float* __restrict__ rnnT, float* __restrict__ logits){
  __shared__ float red[8][32][17];
  int tid = threadIdx.x;
  int jt = tid & 31, ks = tid >> 5;
  int B0 = blockIdx.x * 32;
  int j = B0 + jt;
  const float* wp = Wl + (size_t)(ks*128)*VP1 + (j < VP1 ? j : VP1-1);
  const float4* rT = reinterpret_cast<const float4*>(rnnT) + (size_t)(ks*128)*4;
  float acc[16];
  #pragma unroll
  for (int b=0;b<16;++b) acc[b]=0.f;
  #pragma unroll 2
  for (int kk=0; kk<128; ++kk){
    float w = wp[0]; wp += VP1;
    float4 r0 = rT[0], r1 = rT[1], r2 = rT[2], r3 = rT[3]; rT += 4;
    acc[0]=fmaf(r0.x,w,acc[0]);  acc[1]=fmaf(r0.y,w,acc[1]);
    acc[2]=fmaf(r0.z,w,acc[2]);  acc[3]=fmaf(r0.w,w,acc[3]);
    acc[4]=fmaf(r1.x,w,acc[4]);  acc[5]=fmaf(r1.y,w,acc[5]);
    acc[6]=fmaf(r1.z,w,acc[6]);  acc[7]=fmaf(r1.w,w,acc[7]);
    acc[8]=fmaf(r2.x,w,acc[8]);  acc[9]=fmaf(r2.y,w,acc[9]);
    acc[10]=fmaf(r2.z,w,acc[10]); acc[11]=fmaf(r2.w,w,acc[11]);
    acc[12]=fmaf(r3.x,w,acc[12]); acc[13]=fmaf(r3.y,w,acc[13]);
    acc[14]=fmaf(r3.z,w,acc[14]); acc[15]=fmaf(r3.w,w,acc[15]);
  }
  #pragma unroll
  for (int b=0;b<16;++b) red[ks][jt][b] = acc[b];
  __syncthreads();
  #pragma unroll
  for (int u=0;u<2;++u){
    int o = tid*2+u; int jj = o>>4, b = o&15;
    float s = 0.f;
    #pragma unroll
    for (int x=0;x<8;++x) s += red[x][jj][b];
    int jg = B0 + jj;
    if (jg < VP1) logits[(size_t)b*VP1R + jg] = s;
  }
}

// ---------------- K2a: per-tile LSE partials (49 x 16 blocks) ----------------
__global__ __launch_bounds__(256) void k2a_lsepart(const float* __restrict__ logits,
    float* __restrict__ blkM, float* __restrict__ blkS){
  int tile = blockIdx.x, b = blockIdx.y;
  int tid = threadIdx.x;
  const float* lr = logits + (size_t)b*VP1R + tile*1024;
  int lim = VP1 - tile*1024;
  float m = -INFINITY, s = 0.f;
  #pragma unroll
  for (int c=0;c<4;++c){
    int j = c*256 + tid;
    if (j < lim){
      float x = lr[j];
      if (x > m){ s = s*expf(m-x) + 1.f; m = x; }
      else s += expf(x-m);
    }
  }
  #pragma unroll
  for (int off=32; off; off>>=1){
    float m2 = __shfl_down(m, off), s2 = __shfl_down(s, off);
    lsecomb(m, s, m2, s2);
  }
  __shared__ float wm[4], ws[4];
  int w = tid >> 6;
  if ((tid & 63) == 0){ wm[w] = m; ws[w] = s; }
  __syncthreads();
  if (tid == 0){
    float M = wm[0], S = ws[0];
    lsecomb(M, S, wm[1], ws[1]);
    lsecomb(M, S, wm[2], ws[2]);
    lsecomb(M, S, wm[3], ws[3]);
    blkM[b*LSE_TILES + tile] = M; blkS[b*LSE_TILES + tile] = S;
  }
}

// ---------------- K2b: lse combine (blocks 0-15) + det head (blocks 16-31) ---
__global__ __launch_bounds__(512) void k2b_lse_det(P p, int t){
  int bx = blockIdx.x, tid = threadIdx.x;
  if (bx < 16){
    if (tid < 64){
      int b = bx;
      float m = -INFINITY, s = 0.f;
      if (tid < LSE_TILES){ m = p.blkM[b*LSE_TILES + tid]; s = p.blkS[b*LSE_TILES + tid]; }
      #pragma unroll
      for (int off=32; off; off>>=1){
        float m2 = __shfl_down(m, off), s2 = __shfl_down(s, off);
        lsecomb(m, s, m2, s2);
      }
      if (tid == 0) p.lse[b] = m + logf(s);
    }
    return;
  }
  int b = bx - 16;
  __shared__ float dred[4][129];
  __shared__ float ddet[128];
  int jj = tid & 127, ks = tid >> 7;
  if (t == 0){
    if (tid < 128) ddet[tid] = (tid < RP1) ? p.det0[b*RP1 + tid] : -INFINITY;
    __syncthreads();
  } else {
    float a = 0.f;
    if (jj < RP1){
      const float* hr = p.hst + b*ND;
      for (int k=ks*256; k<ks*256+256; ++k)
        a = fmaf(hr[k], p.Wd[(size_t)k*RP1 + jj], a);
    }
    dred[ks][jj] = a;
    __syncthreads();
    if (tid < 128)
      ddet[tid] = (tid < RP1) ? (dred[0][tid]+dred[1][tid]+dred[2][tid]+dred[3][tid]) : -INFINITY;
    __syncthreads();
  }
  if (tid < 64){
    float a = ddet[tid], a2 = ddet[tid+64];
    float m = fmaxf(a, a2);
    #pragma unroll
    for (int off=32; off; off>>=1) m = fmaxf(m, __shfl_down(m, off));
    m = __shfl(m, 0);
    float e1 = (tid < RP1) ? expf(a - m) : 0.f;
    float e2 = (tid+64 < RP1) ? expf(a2 - m) : 0.f;
    float s = e1 + e2;
    #pragma unroll
    for (int off=32; off; off>>=1) s += __shfl_down(s, off);
    s = __shfl(s, 0);
    float ls = logf(s);
    if (tid < RP1)     p.dlp[b*RP1 + tid]      = a  - m - ls;
    if (tid+64 < RP1)  p.dlp[b*RP1 + tid + 64] = a2 - m - ls;
  }
}

// ------- K3: candidates + per-block top16 (13 slices x 16 beams = 208 blocks) -
__global__ __launch_bounds__(256) void k3_cand(P p, int t){
  int tid = threadIdx.x;
  int slice = blockIdx.x, b = blockIdx.y;
  float lv[16]; unsigned lf[16];
  float cA = p.lpsum[b] - p.lse[b] + p.dlp[b*RP1];
  float cB = p.lpsum[b];
  bool dead = (t==0 && b>0);
  const float* lrow = p.logits + (size_t)b*VP1R;
  const float* drow = p.dlp + b*RP1;
  unsigned fbase = (unsigned)(b*VTT);
  int j0 = slice*4096 + (tid<<2);
  #pragma unroll
  for (int c=0;c<4;++c){
    int j = j0 + c*1024;
    bool vec = (j+4 <= VP1);
    float4 lg = make_float4(0.f,0.f,0.f,0.f);
    if (vec) lg = *reinterpret_cast<const float4*>(lrow + j);
    float le[4] = {lg.x, lg.y, lg.z, lg.w};
    #pragma unroll
    for (int e=0;e<4;++e){
      int jj = j + e;
      float v; unsigned f;
      if (jj < VP1){ v = cA + (vec ? le[e] : lrow[jj]); f = fbase + (unsigned)jj; }
      else if (jj < VTT){ v = cB + drow[jj - NV]; f = fbase + (unsigned)jj; }
      else { v = -3e38f; f = 0xFFFFFFFFu; }
      if (dead && f != 0xFFFFFFFFu) v = NEGF;
      lv[c*4+e] = v; lf[c*4+e] = f;
    }
  }
  __shared__ float wmv[4]; __shared__ unsigned wmf[4];
  __shared__ float sbv; __shared__ unsigned sbf;
  int lane = tid & 63, wid = tid >> 6;
  int blin = b*NSLICE + slice;
  for (int r=0;r<16;++r){
    float bv = lv[0]; unsigned bf = lf[0];
    #pragma unroll
    for (int u=1;u<16;++u) if (better(lv[u],lf[u],bv,bf)){ bv=lv[u]; bf=lf[u]; }
    #pragma unroll
    for (int off=32; off; off>>=1){
      float ov = __shfl_down(bv, off); unsigned of = __shfl_down(bf, off);
      if (better(ov,of,bv,bf)){ bv=ov; bf=of; }
    }
    if (lane==0){ wmv[wid]=bv; wmf[wid]=bf; }
    __syncthreads();
    if (tid==0){
      float mv2=wmv[0]; unsigned mf2=wmf[0];
      #pragma unroll
      for (int w=1;w<4;++w) if (better(wmv[w],wmf[w],mv2,mf2)){ mv2=wmv[w]; mf2=wmf[w]; }
      p.pkv[blin*16+r]=mv2; p.pkf[blin*16+r]=mf2;
      sbv=mv2; sbf=mf2;
    }
    __syncthreads();
    unsigned WF = sbf;
    #pragma unroll
    for (int u=0;u<16;++u) if (lf[u]==WF){ lv[u]=-3e38f; lf[u]=0xFFFFFFFFu; }
  }
}

// ------- K4: redundant global merge + per-beam state + attention (16 x 1024) --
__global__ __launch_bounds__(1024) void k4_beam(P p, int t){
  int bi = blockIdx.x, tid = threadIdx.x;
  float ev[4]; unsigned ef[4];
  #pragma unroll
  for (int c=0;c<4;++c){
    int idx = c*1024 + tid;
    if (idx < MERGE_N){ ev[c]=p.pkv[idx]; ef[c]=p.pkf[idx]; }
    else { ev[c]=-3e38f; ef[c]=0xFFFFFFFFu; }
  }
  __shared__ float wmv[16]; __shared__ unsigned wmf[16];
  __shared__ unsigned sbf;
  __shared__ int wq[16], wc[16]; __shared__ float wvv[16];
  __shared__ float hhs[ND];
  __shared__ float att[128];
  __shared__ float msk[RP1];
  __shared__ int s_q, s_it; __shared__ float s_local;
  int lane = tid & 63, wid = tid >> 6;
  for (int r=0;r<16;++r){
    float bv = ev[0]; unsigned bf = ef[0];
    #pragma unroll
    for (int c=1;c<4;++c) if (better(ev[c],ef[c],bv,bf)){ bv=ev[c]; bf=ef[c]; }
    #pragma unroll
    for (int off=32; off; off>>=1){
      float ov = __shfl_down(bv, off); unsigned of = __shfl_down(bf, off);
      if (better(ov,of,bv,bf)){ bv=ov; bf=of; }
    }
    if (lane==0){ wmv[wid]=bv; wmf[wid]=bf; }
    __syncthreads();
    if (tid==0){
      float mv2=wmv[0]; unsigned mf2=wmf[0];
      #pragma unroll
      for (int w=1;w<16;++w) if (better(wmv[w],wmf[w],mv2,mf2)){ mv2=wmv[w]; mf2=wmf[w]; }
      unsigned q = mf2 / VTT; unsigned c = mf2 - q*VTT;
      wq[r]=(int)q; wc[r]=(int)c; wvv[r]=mv2;
      sbf=mf2;
    }
    __syncthreads();
    unsigned WF = sbf;
    #pragma unroll
    for (int c=0;c<4;++c) if (ef[c]==WF){ ev[c]=-3e38f; ef[c]=0xFFFFFFFFu; }
  }
  if (tid == 0){
    int q = wq[bi], c = wc[bi];
    float local = (c < VP1) ? (p.logits[(size_t)q*VP1R + c] - p.lse[q] + p.dlp[q*RP1])
                            : p.dlp[q*RP1 + (c - NV)];
    int it = (c > NV) ? ((int)p.ppls[((size_t)bi*NR + (c - VP1))*6 + 4] + NV) : c;
    s_q = q; s_it = it; s_local = local;
    p.lpsum[bi] = (c==0) ? -1000.0f : wvv[bi];
  }
  __syncthreads();
  int q = s_q, c = wc[bi], it = s_it;
  // beam_seq / beam_lp reshuffle (this beam's column only)
  const int*   bss = (t&1)? p.bs1 : p.bs0;   int*   bsd = (t&1)? p.bs0 : p.bs1;
  const float* lps = (t&1)? p.blp1: p.blp0;  float* lpd = (t&1)? p.blp0: p.blp1;
  if (tid < t){ bsd[tid*NB+bi] = bss[tid*NB+q]; lpd[tid*NB+bi] = lps[tid*NB+q]; }
  if (tid == t){ bsd[t*NB+bi] = c; lpd[t*NB+bi] = s_local; }
  // mask gather + ROI scatter
  const float* ms = (t==0) ? p.pnt : ((t&1)? p.mask1 : p.mask0);
  float* md = (t&1)? p.mask0 : p.mask1;
  if (tid < RP1){
    float m = ms[q*RP1 + tid];
    if (tid == 0) m = 0.f;
    if (c > NV && tid == (c - VP1) + 1) m = 1.0f;
    msk[tid] = m; md[bi*RP1 + tid] = m;
  }
  // hh gather + xt embed
  const float* hprev = (t==0) ? p.h0 : p.hst;
  float hv = hprev[(size_t)q*ND + tid];
  hhs[tid] = hv;
  p.hhgT[tid*NB + bi] = hv;
  p.xtT[tid*NB + bi] = p.embed[(size_t)it*ND + tid];
  if (tid >= 100 && tid < 128) att[tid] = -INFINITY;
  __syncthreads();
  int w = tid >> 6, l = tid & 63;
  for (int r=w; r<NR; r+=16){
    const float* pf = p.pool + ((size_t)bi*NR + r)*ND;
    float s = 0.f;
    #pragma unroll
    for (int cc=0;cc<4;++cc){
      float4 pv = *reinterpret_cast<const float4*>(pf + cc*256 + l*4);
      float4 hvv = *reinterpret_cast<const float4*>(&hhs[cc*256 + l*4]);
      s = fmaf(pv.x,hvv.x,s); s = fmaf(pv.y,hvv.y,s);
      s = fmaf(pv.z,hvv.z,s); s = fmaf(pv.w,hvv.w,s);
    }
    #pragma unroll
    for (int off=32; off; off>>=1) s += __shfl_down(s, off);
    if (l == 0) att[r] = (msk[r+1] > 0.f) ? NEGF : s*0.03125f;
  }
  __syncthreads();
  if (tid < 64){
    float a = att[tid], a2 = att[tid+64];
    float m = fmaxf(a, a2);
    #pragma unroll
    for (int off=32; off; off>>=1) m = fmaxf(m, __shfl_down(m, off));
    m = __shfl(m, 0);
    float e1 = expf(a - m);
    float e2 = (tid+64 < 128) ? expf(a2 - m) : 0.f;
    float s = e1 + e2;
    #pragma unroll
    for (int off=32; off; off>>=1) s += __shfl_down(s, off);
    s = __shfl(s, 0);
    att[tid] = e1 / s;
    att[tid+64] = e2 / s;
  }
  __syncthreads();
  float cx = 0.f;
  const float* pb = p.pool + (size_t)bi*NR*ND + tid;
  #pragma unroll 4
  for (int r=0;r<NR;++r) cx = fmaf(att[r], pb[(size_t)r*ND], cx);
  p.ctxT[tid*NB + bi] = cx;
}

// ---------------- K5: fused 3-matrix RNN GEMM partials (128 blocks) ----------
__global__ __launch_bounds__(256) void k5_rnn(const float* __restrict__ Wx,
    const float* __restrict__ Wh, const float* __restrict__ Wc,
    const float* __restrict__ xtT, const float* __restrict__ hhgT,
    const float* __restrict__ ctxT, float* __restrict__ part){
  int tid = threadIdx.x;
  int jb = blockIdx.x & 3, ks = blockIdx.x >> 2;
  int j = jb*256 + tid;
  int k0 = ks*32;
  float acc[16];
  #pragma unroll
  for (int b=0;b<16;++b) acc[b]=0.f;
  for (int k=k0;k<k0+32;++k){
    float wx = Wx[(size_t)k*ND + j];
    float wh = Wh[(size_t)k*ND + j];
    float wc = Wc[(size_t)k*ND + j];
    const float4* xv = reinterpret_cast<const float4*>(xtT)  + (size_t)k*4;
    const float4* hv = reinterpret_cast<const float4*>(hhgT) + (size_t)k*4;
    const float4* cv = reinterpret_cast<const float4*>(ctxT) + (size_t)k*4;
    float4 x0=xv[0],x1=xv[1],x2=xv[2],x3=xv[3];
    float4 h0=hv[0],h1=hv[1],h2=hv[2],h3=hv[3];
    float4 c0=cv[0],c1=cv[1],c2=cv[2],c3=cv[3];
    acc[0]=fmaf(x0.x,wx,fmaf(h0.x,wh,fmaf(c0.x,wc,acc[0])));
    acc[1]=fmaf(x0.y,wx,fmaf(h0.y,wh,fmaf(c0.y,wc,acc[1])));
    acc[2]=fmaf(x0.z,wx,fmaf(h0.z,wh,fmaf(c0.z,wc,acc[2])));
    acc[3]=fmaf(x0.w,wx,fmaf(h0.w,wh,fmaf(c0.w,wc,acc[3])));
    acc[4]=fmaf(x1.x,wx,fmaf(h1.x,wh,fmaf(c1.x,wc,acc[4])));
    acc[5]=fmaf(x1.y,wx,fmaf(h1.y,wh,fmaf(c1.y,wc,acc[5])));
    acc[6]=fmaf(x1.z,wx,fmaf(h1.z,wh,fmaf(c1.z,wc,acc[6])));
    acc[7]=fmaf(x1.w,wx,fmaf(h1.w,wh,fmaf(c1.w,wc,acc[7])));
    acc[8]=fmaf(x2.x,wx,fmaf(h2.x,wh,fmaf(c2.x,wc,acc[8])));
    acc[9]=fmaf(x2.y,wx,fmaf(h2.y,wh,fmaf(c2.y,wc,acc[9])));
    acc[10]=fmaf(x2.z,wx,fmaf(h2.z,wh,fmaf(c2.z,wc,acc[10])));
    acc[11]=fmaf(x2.w,wx,fmaf(h2.w,wh,fmaf(c2.w,wc,acc[11])));
    acc[12]=fmaf(x3.x,wx,fmaf(h3.x,wh,fmaf(c3.x,wc,acc[12])));
    acc[13]=fmaf(x3.y,wx,fmaf(h3.y,wh,fmaf(c3.y,wc,acc[13])));
    acc[14]=fmaf(x3.z,wx,fmaf(h3.z,wh,fmaf(c3.z,wc,acc[14])));
    acc[15]=fmaf(x3.w,wx,fmaf(h3.w,wh,fmaf(c3.w,wc,acc[15])));
  }
  #pragma unroll
  for (int b=0;b<16;++b) part[((size_t)ks*16 + b)*ND + j] = acc[b];
}

// ---------------- K6: reduce partials + tanh -> h_new ----------------
__global__ __launch_bounds__(256) void k6_tanh(P p){
  int o = blockIdx.x*256 + threadIdx.x;
  int b = o >> 10, j = o & 1023;
  float s = 0.f;
  for (int ks=0; ks<32; ++ks) s += p.part[((size_t)ks*16 + b)*ND + j];
  float hv = tanhf(s);
  p.hst[o] = hv;
  p.rnnT[j*NB + b] = hv;
}

// ---------------- K7: pack outputs (f32) ----------------
__global__ __launch_bounds__(256) void k7_out(P p, float* out){
  int i = blockIdx.x*256 + threadIdx.x;
  if (i < NT*NB)            out[i] = (float)p.bs0[i];
  else if (i < 2*NT*NB)     out[i] = p.blp0[i - NT*NB];
  else if (i < 2*NT*NB+NB)  out[i] = p.lpsum[i - 2*NT*NB];
}

// ---------------- host ----------------
extern "C" void kernel_launch(void* const* d_in, const int* in_sizes, int n_in,
                              void* d_out, int out_size, void* d_ws, size_t ws_size,
                              hipStream_t stream) {
  P p;
  p.embed = (const float*)d_in[0];
  p.Wx    = (const float*)d_in[1];
  p.Wh    = (const float*)d_in[2];
  p.Wc    = (const float*)d_in[3];
  p.Wl    = (const float*)d_in[4];
  p.Wd    = (const float*)d_in[5];
  p.rnn0  = (const float*)d_in[6];
  p.det0  = (const float*)d_in[7];
  p.h0    = (const float*)d_in[8];
  p.pool  = (const float*)d_in[9];
  p.ppls  = (const float*)d_in[10];
  p.pnt   = (const float*)d_in[11];

  char* ws = (char*)d_ws;
  size_t off = 0;
  auto A = [&](size_t nfloats)->void* {
    void* r = ws + off;
    off += ((nfloats*4) + 255) & ~(size_t)255;
    return r;
  };
  p.logits = (float*)A((size_t)NB*VP1R);
  p.lse    = (float*)A(NB);
  p.dlp    = (float*)A(NB*RP1);
  p.rnnT   = (float*)A(ND*NB);
  p.hst    = (float*)A(NB*ND);
  p.hhgT   = (float*)A(ND*NB);
  p.xtT    = (float*)A(ND*NB);
  p.ctxT   = (float*)A(ND*NB);
  p.mask0  = (float*)A(NB*RP1);
  p.mask1  = (float*)A(NB*RP1);
  p.bs0    = (int*)A(NT*NB);
  p.bs1    = (int*)A(NT*NB);
  p.blp0   = (float*)A(NT*NB);
  p.blp1   = (float*)A(NT*NB);
  p.lpsum  = (float*)A(NB);
  p.pkv    = (float*)A(MERGE_N);
  p.pkf    = (unsigned*)A(MERGE_N);
  p.part   = (float*)A((size_t)32*NB*ND);
  p.blkM   = (float*)A(NB*LSE_TILES);
  p.blkS   = (float*)A(NB*LSE_TILES);
  if (off > ws_size) return;

  k0_init<<<64,256,0,stream>>>(p);
  for (int t=0; t<NT; ++t){
    k1_logits<<<(VP1+31)/32,256,0,stream>>>(p.Wl, p.rnnT, p.logits);
    k2a_lsepart<<<dim3(LSE_TILES,NB),256,0,stream>>>(p.logits, p.blkM, p.blkS);
    k2b_lse_det<<<32,512,0,stream>>>(p, t);
    k3_cand<<<dim3(NSLICE,NB),256,0,stream>>>(p, t);
    k4_beam<<<NB,1024,0,stream>>>(p, t);
    k5_rnn<<<128,256,0,stream>>>(p.Wx, p.Wh, p.Wc, p.xtT, p.hhgT, p.ctxT, p.part);
    k6_tanh<<<64,256,0,stream>>>(p);
  }
  k7_out<<<3,256,0,stream>>>(p, (float*)d_out);
}

// Round 6
// 3418.648 us; speedup vs baseline: 1.2672x; 1.2672x over previous
//
#include <hip/hip_runtime.h>
#include <math.h>

#define NB 16
#define NR 100
#define NV 50000
#define ND 1024
#define NT 20
#define VP1 50001
#define VP1R 50004     // padded row stride (float4-aligned rows)
#define VTT 50101
#define RP1 101
#define NEGF (-1e10f)
#define LSE_TILES 49   // ceil(50001/1024)
#define NSLICE 13      // 13*4096 = 53248 >= 50101
#define NBLK3 (NB*NSLICE)      // 208
#define MERGE_N (NBLK3*16)     // 3328
#define KSPLIT 4

struct P {
  const float* embed; const float* Wx; const float* Wh; const float* Wc;
  const float* Wl; const float* Wd; const float* rnn0; const float* det0;
  const float* h0; const float* pool; const float* ppls; const float* pnt;
  float* logits;   // [16][VP1R]
  float* lse;      // [16]
  float* dlp;      // [16][101]
  float* rnnT;     // [1024][16]
  float* hst;      // [16][1024]
  float* hhgT;     // [1024][16]
  float* xtT;      // [1024][16]
  float* ctxT;     // [1024][16]
  float* mask0; float* mask1;       // [16][101] ping-pong
  int* bs0; int* bs1;               // [20][16] ping-pong
  float* blp0; float* blp1;         // [20][16] ping-pong
  float* lpsum;    // [16]
  float* pkv; unsigned* pkf;        // [MERGE_N]
  float* part;     // [32][16][1024] (k5 partials)
  float* partL;    // [KSPLIT][16][VP1R] (k1 partials)
  float* blkM; float* blkS;         // [16*49]
};

__device__ __forceinline__ bool better(float av, unsigned af, float bv, unsigned bf){
  return (av > bv) || (av == bv && af < bf);
}
__device__ __forceinline__ void lsecomb(float& m, float& s, float m2, float s2){
  float M = fmaxf(m, m2);
  if (M == -INFINITY){ m = M; s = 0.f; return; }
  s = s*expf(m - M) + s2*expf(m2 - M);
  m = M;
}

// ---------------- K0: init ----------------
__global__ __launch_bounds__(256) void k0_init(P p){
  int i = blockIdx.x*256 + threadIdx.x;
  int n = gridDim.x*256;
  for (int o=i; o<NB*ND; o+=n){ int b=o>>10, k=o&1023; p.rnnT[k*NB+b] = p.rnn0[o]; }
  for (int o=i; o<NT*NB; o+=n){ p.bs0[o]=0; p.bs1[o]=0; p.blp0[o]=0.f; p.blp1[o]=0.f; }
  for (int o=i; o<NB; o+=n) p.lpsum[o]=0.f;
}

// ---------------- K1 helpers ----------------
__device__ __forceinline__ void ld16(const float* __restrict__ wp, float* w){
  const float* q = wp;
  #pragma unroll
  for (int u=0;u<16;++u){ w[u] = *q; q += VP1; }
}
__device__ __forceinline__ void fma16(const float4* __restrict__ lr, int KB,
                                      const float* w, float* acc){
  #pragma unroll
  for (int u=0;u<16;++u){
    float4 r0 = lr[(KB+u)*4+0];
    float4 r1 = lr[(KB+u)*4+1];
    float4 r2 = lr[(KB+u)*4+2];
    float4 r3 = lr[(KB+u)*4+3];
    float wv = w[u];
    acc[0]=fmaf(r0.x,wv,acc[0]);  acc[1]=fmaf(r0.y,wv,acc[1]);
    acc[2]=fmaf(r0.z,wv,acc[2]);  acc[3]=fmaf(r0.w,wv,acc[3]);
    acc[4]=fmaf(r1.x,wv,acc[4]);  acc[5]=fmaf(r1.y,wv,acc[5]);
    acc[6]=fmaf(r1.z,wv,acc[6]);  acc[7]=fmaf(r1.w,wv,acc[7]);
    acc[8]=fmaf(r2.x,wv,acc[8]);  acc[9]=fmaf(r2.y,wv,acc[9]);
    acc[10]=fmaf(r2.z,wv,acc[10]); acc[11]=fmaf(r2.w,wv,acc[11]);
    acc[12]=fmaf(r3.x,wv,acc[12]); acc[13]=fmaf(r3.y,wv,acc[13]);
    acc[14]=fmaf(r3.z,wv,acc[14]); acc[15]=fmaf(r3.w,wv,acc[15]);
  }
}

// ---------------- K1: partial logits = rnn_out @ Wl (k-split 4 across blocks) -
// grid (4, 196) x 256 thr. LDS-staged rnnT slice; 16-deep double-buffered
// Wl load pipeline -> 4 KB outstanding per wave during every FMA block.
__global__ __launch_bounds__(256) void k1_logits(const float* __restrict__ Wl,
    const float* __restrict__ rnnT, float* __restrict__ partL){
  __shared__ float rlds[256*16];
  int tid = threadIdx.x;
  int g = blockIdx.x;        // k-group 0..3
  int jt = blockIdx.y;       // j-tile 0..195
  int k0 = g*256;
  const float4* r4 = reinterpret_cast<const float4*>(rnnT) + (size_t)k0*4;
  float4* l4 = reinterpret_cast<float4*>(rlds);
  #pragma unroll
  for (int i=0;i<4;++i) l4[i*256+tid] = r4[i*256+tid];
  __syncthreads();
  int j = jt*256 + tid;
  bool jok = (j < VP1);
  const float* wp = Wl + (size_t)k0*VP1 + (jok ? j : (VP1-1));
  float acc[16];
  #pragma unroll
  for (int b=0;b<16;++b) acc[b]=0.f;
  float wa[16], wb[16];
  const float4* lr = reinterpret_cast<const float4*>(rlds);
  ld16(wp, wa); wp += (size_t)16*VP1;
  #pragma unroll 1
  for (int bt=0; bt<8; ++bt){
    ld16(wp, wb); wp += (size_t)16*VP1;
    fma16(lr, bt*32, wa, acc);
    if (bt < 7){ ld16(wp, wa); wp += (size_t)16*VP1; }
    fma16(lr, bt*32+16, wb, acc);
  }
  if (jok){
    float* pb = partL + (size_t)(g*16)*VP1R + j;
    #pragma unroll
    for (int b=0;b<16;++b) pb[(size_t)b*VP1R] = acc[b];
  }
}

// -------- K2a: sum k-partials -> logits + per-tile online LSE (49 x 16) ------
__global__ __launch_bounds__(256) void k2a_sum_lse(const float* __restrict__ partL,
    float* __restrict__ logits, float* __restrict__ blkM, float* __restrict__ blkS){
  int tile = blockIdx.x, b = blockIdx.y, tid = threadIdx.x;
  int j0 = tile*1024 + tid*4;
  float m = -INFINITY, s = 0.f;
  if (j0 < VP1){
    const float4* base = reinterpret_cast<const float4*>(partL);
    const size_t pstride = VP1R/4;
    size_t jq = (size_t)(j0 >> 2);
    float4 a0 = base[(size_t)(0*16+b)*pstride + jq];
    float4 a1 = base[(size_t)(1*16+b)*pstride + jq];
    float4 a2 = base[(size_t)(2*16+b)*pstride + jq];
    float4 a3 = base[(size_t)(3*16+b)*pstride + jq];
    float4 sm4;
    sm4.x = a0.x+a1.x+a2.x+a3.x;
    sm4.y = a0.y+a1.y+a2.y+a3.y;
    sm4.z = a0.z+a1.z+a2.z+a3.z;
    sm4.w = a0.w+a1.w+a2.w+a3.w;
    reinterpret_cast<float4*>(logits)[(size_t)b*pstride + jq] = sm4;
    float vals[4] = {sm4.x, sm4.y, sm4.z, sm4.w};
    #pragma unroll
    for (int e=0;e<4;++e){
      if (j0+e < VP1){
        float x = vals[e];
        if (x > m){ s = s*expf(m-x) + 1.f; m = x; }
        else s += expf(x-m);
      }
    }
  }
  #pragma unroll
  for (int off=32; off; off>>=1){
    float m2 = __shfl_down(m, off), s2 = __shfl_down(s, off);
    lsecomb(m, s, m2, s2);
  }
  __shared__ float wm[4], ws2[4];
  int w = tid >> 6;
  if ((tid & 63) == 0){ wm[w] = m; ws2[w] = s; }
  __syncthreads();
  if (tid == 0){
    float M = wm[0], S = ws2[0];
    lsecomb(M, S, wm[1], ws2[1]);
    lsecomb(M, S, wm[2], ws2[2]);
    lsecomb(M, S, wm[3], ws2[3]);
    blkM[b*LSE_TILES + tile] = M; blkS[b*LSE_TILES + tile] = S;
  }
}

// ---------------- K2b: lse combine (blocks 0-15) + det head (blocks 16-31) ---
__global__ __launch_bounds__(512) void k2b_lse_det(P p, int t){
  int bx = blockIdx.x, tid = threadIdx.x;
  if (bx < 16){
    if (tid < 64){
      int b = bx;
      float m = -INFINITY, s = 0.f;
      if (tid < LSE_TILES){ m = p.blkM[b*LSE_TILES + tid]; s = p.blkS[b*LSE_TILES + tid]; }
      #pragma unroll
      for (int off=32; off; off>>=1){
        float m2 = __shfl_down(m, off), s2 = __shfl_down(s, off);
        lsecomb(m, s, m2, s2);
      }
      if (tid == 0) p.lse[b] = m + logf(s);
    }
    return;
  }
  int b = bx - 16;
  __shared__ float dred[4][129];
  __shared__ float ddet[128];
  int jj = tid & 127, ks = tid >> 7;
  if (t == 0){
    if (tid < 128) ddet[tid] = (tid < RP1) ? p.det0[b*RP1 + tid] : -INFINITY;
    __syncthreads();
  } else {
    float a = 0.f;
    if (jj < RP1){
      const float* hr = p.hst + b*ND;
      for (int k=ks*256; k<ks*256+256; ++k)
        a = fmaf(hr[k], p.Wd[(size_t)k*RP1 + jj], a);
    }
    dred[ks][jj] = a;
    __syncthreads();
    if (tid < 128)
      ddet[tid] = (tid < RP1) ? (dred[0][tid]+dred[1][tid]+dred[2][tid]+dred[3][tid]) : -INFINITY;
    __syncthreads();
  }
  if (tid < 64){
    float a = ddet[tid], a2 = ddet[tid+64];
    float m = fmaxf(a, a2);
    #pragma unroll
    for (int off=32; off; off>>=1) m = fmaxf(m, __shfl_down(m, off));
    m = __shfl(m, 0);
    float e1 = (tid < RP1) ? expf(a - m) : 0.f;
    float e2 = (tid+64 < RP1) ? expf(a2 - m) : 0.f;
    float s = e1 + e2;
    #pragma unroll
    for (int off=32; off; off>>=1) s += __shfl_down(s, off);
    s = __shfl(s, 0);
    float ls = logf(s);
    if (tid < RP1)     p.dlp[b*RP1 + tid]      = a  - m - ls;
    if (tid+64 < RP1)  p.dlp[b*RP1 + tid + 64] = a2 - m - ls;
  }
}

// ------- K3: candidates + per-block top16 (13 slices x 16 beams = 208 blocks) -
__global__ __launch_bounds__(256) void k3_cand(P p, int t){
  int tid = threadIdx.x;
  int slice = blockIdx.x, b = blockIdx.y;
  float lv[16]; unsigned lf[16];
  float cA = p.lpsum[b] - p.lse[b] + p.dlp[b*RP1];
  float cB = p.lpsum[b];
  bool dead = (t==0 && b>0);
  const float* lrow = p.logits + (size_t)b*VP1R;
  const float* drow = p.dlp + b*RP1;
  unsigned fbase = (unsigned)(b*VTT);
  int j0 = slice*4096 + (tid<<2);
  #pragma unroll
  for (int c=0;c<4;++c){
    int j = j0 + c*1024;
    bool vec = (j+4 <= VP1);
    float4 lg = make_float4(0.f,0.f,0.f,0.f);
    if (vec) lg = *reinterpret_cast<const float4*>(lrow + j);
    float le[4] = {lg.x, lg.y, lg.z, lg.w};
    #pragma unroll
    for (int e=0;e<4;++e){
      int jj = j + e;
      float v; unsigned f;
      if (jj < VP1){ v = cA + (vec ? le[e] : lrow[jj]); f = fbase + (unsigned)jj; }
      else if (jj < VTT){ v = cB + drow[jj - NV]; f = fbase + (unsigned)jj; }
      else { v = -3e38f; f = 0xFFFFFFFFu; }
      if (dead && f != 0xFFFFFFFFu) v = NEGF;
      lv[c*4+e] = v; lf[c*4+e] = f;
    }
  }
  __shared__ float wmv[4]; __shared__ unsigned wmf[4];
  __shared__ float sbv; __shared__ unsigned sbf;
  int lane = tid & 63, wid = tid >> 6;
  int blin = b*NSLICE + slice;
  for (int r=0;r<16;++r){
    float bv = lv[0]; unsigned bf = lf[0];
    #pragma unroll
    for (int u=1;u<16;++u) if (better(lv[u],lf[u],bv,bf)){ bv=lv[u]; bf=lf[u]; }
    #pragma unroll
    for (int off=32; off; off>>=1){
      float ov = __shfl_down(bv, off); unsigned of = __shfl_down(bf, off);
      if (better(ov,of,bv,bf)){ bv=ov; bf=of; }
    }
    if (lane==0){ wmv[wid]=bv; wmf[wid]=bf; }
    __syncthreads();
    if (tid==0){
      float mv2=wmv[0]; unsigned mf2=wmf[0];
      #pragma unroll
      for (int w=1;w<4;++w) if (better(wmv[w],wmf[w],mv2,mf2)){ mv2=wmv[w]; mf2=wmf[w]; }
      p.pkv[blin*16+r]=mv2; p.pkf[blin*16+r]=mf2;
      sbv=mv2; sbf=mf2;
    }
    __syncthreads();
    unsigned WF = sbf;
    #pragma unroll
    for (int u=0;u<16;++u) if (lf[u]==WF){ lv[u]=-3e38f; lf[u]=0xFFFFFFFFu; }
  }
}

// ------- K4: redundant global merge + per-beam state + attention (16 x 1024) --
__global__ __launch_bounds__(1024) void k4_beam(P p, int t){
  int bi = blockIdx.x, tid = threadIdx.x;
  float ev[4]; unsigned ef[4];
  #pragma unroll
  for (int c=0;c<4;++c){
    int idx = c*1024 + tid;
    if (idx < MERGE_N){ ev[c]=p.pkv[idx]; ef[c]=p.pkf[idx]; }
    else { ev[c]=-3e38f; ef[c]=0xFFFFFFFFu; }
  }
  __shared__ float wmv[16]; __shared__ unsigned wmf[16];
  __shared__ unsigned sbf;
  __shared__ int wq[16], wc[16]; __shared__ float wvv[16];
  __shared__ float hhs[ND];
  __shared__ float att[128];
  __shared__ float msk[RP1];
  __shared__ int s_q, s_it; __shared__ float s_local;
  int lane = tid & 63, wid = tid >> 6;
  for (int r=0;r<16;++r){
    float bv = ev[0]; unsigned bf = ef[0];
    #pragma unroll
    for (int c=1;c<4;++c) if (better(ev[c],ef[c],bv,bf)){ bv=ev[c]; bf=ef[c]; }
    #pragma unroll
    for (int off=32; off; off>>=1){
      float ov = __shfl_down(bv, off); unsigned of = __shfl_down(bf, off);
      if (better(ov,of,bv,bf)){ bv=ov; bf=of; }
    }
    if (lane==0){ wmv[wid]=bv; wmf[wid]=bf; }
    __syncthreads();
    if (tid==0){
      float mv2=wmv[0]; unsigned mf2=wmf[0];
      #pragma unroll
      for (int w=1;w<16;++w) if (better(wmv[w],wmf[w],mv2,mf2)){ mv2=wmv[w]; mf2=wmf[w]; }
      unsigned q = mf2 / VTT; unsigned c = mf2 - q*VTT;
      wq[r]=(int)q; wc[r]=(int)c; wvv[r]=mv2;
      sbf=mf2;
    }
    __syncthreads();
    unsigned WF = sbf;
    #pragma unroll
    for (int c=0;c<4;++c) if (ef[c]==WF){ ev[c]=-3e38f; ef[c]=0xFFFFFFFFu; }
  }
  if (tid == 0){
    int q = wq[bi], c = wc[bi];
    float local = (c < VP1) ? (p.logits[(size_t)q*VP1R + c] - p.lse[q] + p.dlp[q*RP1])
                            : p.dlp[q*RP1 + (c - NV)];
    int it = (c > NV) ? ((int)p.ppls[((size_t)bi*NR + (c - VP1))*6 + 4] + NV) : c;
    s_q = q; s_it = it; s_local = local;
    p.lpsum[bi] = (c==0) ? -1000.0f : wvv[bi];
  }
  __syncthreads();
  int q = s_q, c = wc[bi], it = s_it;
  const int*   bss = (t&1)? p.bs1 : p.bs0;   int*   bsd = (t&1)? p.bs0 : p.bs1;
  const float* lps = (t&1)? p.blp1: p.blp0;  float* lpd = (t&1)? p.blp0: p.blp1;
  if (tid < t){ bsd[tid*NB+bi] = bss[tid*NB+q]; lpd[tid*NB+bi] = lps[tid*NB+q]; }
  if (tid == t){ bsd[t*NB+bi] = c; lpd[t*NB+bi] = s_local; }
  const float* ms = (t==0) ? p.pnt : ((t&1)? p.mask1 : p.mask0);
  float* md = (t&1)? p.mask0 : p.mask1;
  if (tid < RP1){
    float m = ms[q*RP1 + tid];
    if (tid == 0) m = 0.f;
    if (c > NV && tid == (c - VP1) + 1) m = 1.0f;
    msk[tid] = m; md[bi*RP1 + tid] = m;
  }
  const float* hprev = (t==0) ? p.h0 : p.hst;
  float hv = hprev[(size_t)q*ND + tid];
  hhs[tid] = hv;
  p.hhgT[tid*NB + bi] = hv;
  p.xtT[tid*NB + bi] = p.embed[(size_t)it*ND + tid];
  if (tid >= 100 && tid < 128) att[tid] = -INFINITY;
  __syncthreads();
  int w = tid >> 6, l = tid & 63;
  for (int r=w; r<NR; r+=16){
    const float* pf = p.pool + ((size_t)bi*NR + r)*ND;
    float s = 0.f;
    #pragma unroll
    for (int cc=0;cc<4;++cc){
      float4 pv = *reinterpret_cast<const float4*>(pf + cc*256 + l*4);
      float4 hvv = *reinterpret_cast<const float4*>(&hhs[cc*256 + l*4]);
      s = fmaf(pv.x,hvv.x,s); s = fmaf(pv.y,hvv.y,s);
      s = fmaf(pv.z,hvv.z,s); s = fmaf(pv.w,hvv.w,s);
    }
    #pragma unroll
    for (int off=32; off; off>>=1) s += __shfl_down(s, off);
    if (l == 0) att[r] = (msk[r+1] > 0.f) ? NEGF : s*0.03125f;
  }
  __syncthreads();
  if (tid < 64){
    float a = att[tid], a2 = att[tid+64];
    float m = fmaxf(a, a2);
    #pragma unroll
    for (int off=32; off; off>>=1) m = fmaxf(m, __shfl_down(m, off));
    m = __shfl(m, 0);
    float e1 = expf(a - m);
    float e2 = (tid+64 < 128) ? expf(a2 - m) : 0.f;
    float s = e1 + e2;
    #pragma unroll
    for (int off=32; off; off>>=1) s += __shfl_down(s, off);
    s = __shfl(s, 0);
    att[tid] = e1 / s;
    att[tid+64] = e2 / s;
  }
  __syncthreads();
  float cx = 0.f;
  const float* pb = p.pool + (size_t)bi*NR*ND + tid;
  #pragma unroll 4
  for (int r=0;r<NR;++r) cx = fmaf(att[r], pb[(size_t)r*ND], cx);
  p.ctxT[tid*NB + bi] = cx;
}

// ---------------- K5: fused 3-matrix RNN GEMM partials (128 blocks) ----------
__global__ __launch_bounds__(256) void k5_rnn(const float* __restrict__ Wx,
    const float* __restrict__ Wh, const float* __restrict__ Wc,
    const float* __restrict__ xtT, const float* __restrict__ hhgT,
    const float* __restrict__ ctxT, float* __restrict__ part){
  int tid = threadIdx.x;
  int jb = blockIdx.x & 3, ks = blockIdx.x >> 2;
  int j = jb*256 + tid;
  int k0 = ks*32;
  float acc[16];
  #pragma unroll
  for (int b=0;b<16;++b) acc[b]=0.f;
  for (int k=k0;k<k0+32;++k){
    float wx = Wx[(size_t)k*ND + j];
    float wh = Wh[(size_t)k*ND + j];
    float wc = Wc[(size_t)k*ND + j];
    const float4* xv = reinterpret_cast<const float4*>(xtT)  + (size_t)k*4;
    const float4* hv = reinterpret_cast<const float4*>(hhgT) + (size_t)k*4;
    const float4* cv = reinterpret_cast<const float4*>(ctxT) + (size_t)k*4;
    float4 x0=xv[0],x1=xv[1],x2=xv[2],x3=xv[3];
    float4 h0=hv[0],h1=hv[1],h2=hv[2],h3=hv[3];
    float4 c0=cv[0],c1=cv[1],c2=cv[2],c3=cv[3];
    acc[0]=fmaf(x0.x,wx,fmaf(h0.x,wh,fmaf(c0.x,wc,acc[0])));
    acc[1]=fmaf(x0.y,wx,fmaf(h0.y,wh,fmaf(c0.y,wc,acc[1])));
    acc[2]=fmaf(x0.z,wx,fmaf(h0.z,wh,fmaf(c0.z,wc,acc[2])));
    acc[3]=fmaf(x0.w,wx,fmaf(h0.w,wh,fmaf(c0.w,wc,acc[3])));
    acc[4]=fmaf(x1.x,wx,fmaf(h1.x,wh,fmaf(c1.x,wc,acc[4])));
    acc[5]=fmaf(x1.y,wx,fmaf(h1.y,wh,fmaf(c1.y,wc,acc[5])));
    acc[6]=fmaf(x1.z,wx,fmaf(h1.z,wh,fmaf(c1.z,wc,acc[6])));
    acc[7]=fmaf(x1.w,wx,fmaf(h1.w,wh,fmaf(c1.w,wc,acc[7])));
    acc[8]=fmaf(x2.x,wx,fmaf(h2.x,wh,fmaf(c2.x,wc,acc[8])));
    acc[9]=fmaf(x2.y,wx,fmaf(h2.y,wh,fmaf(c2.y,wc,acc[9])));
    acc[10]=fmaf(x2.z,wx,fmaf(h2.z,wh,fmaf(c2.z,wc,acc[10])));
    acc[11]=fmaf(x2.w,wx,fmaf(h2.w,wh,fmaf(c2.w,wc,acc[11])));
    acc[12]=fmaf(x3.x,wx,fmaf(h3.x,wh,fmaf(c3.x,wc,acc[12])));
    acc[13]=fmaf(x3.y,wx,fmaf(h3.y,wh,fmaf(c3.y,wc,acc[13])));
    acc[14]=fmaf(x3.z,wx,fmaf(h3.z,wh,fmaf(c3.z,wc,acc[14])));
    acc[15]=fmaf(x3.w,wx,fmaf(h3.w,wh,fmaf(c3.w,wc,acc[15])));
  }
  #pragma unroll
  for (int b=0;b<16;++b) part[((size_t)ks*16 + b)*ND + j] = acc[b];
}

// ---------------- K6: reduce partials + tanh -> h_new ----------------
__global__ __launch_bounds__(256) void k6_tanh(P p){
  int o = blockIdx.x*256 + threadIdx.x;
  int b = o >> 10, j = o & 1023;
  float s = 0.f;
  for (int ks=0; ks<32; ++ks) s += p.part[((size_t)ks*16 + b)*ND + j];
  float hv = tanhf(s);
  p.hst[o] = hv;
  p.rnnT[j*NB + b] = hv;
}

// ---------------- K7: pack outputs (f32) ----------------
__global__ __launch_bounds__(256) void k7_out(P p, float* out){
  int i = blockIdx.x*256 + threadIdx.x;
  if (i < NT*NB)            out[i] = (float)p.bs0[i];
  else if (i < 2*NT*NB)     out[i] = p.blp0[i - NT*NB];
  else if (i < 2*NT*NB+NB)  out[i] = p.lpsum[i - 2*NT*NB];
}

// ---------------- host ----------------
extern "C" void kernel_launch(void* const* d_in, const int* in_sizes, int n_in,
                              void* d_out, int out_size, void* d_ws, size_t ws_size,
                              hipStream_t stream) {
  P p;
  p.embed = (const float*)d_in[0];
  p.Wx    = (const float*)d_in[1];
  p.Wh    = (const float*)d_in[2];
  p.Wc    = (const float*)d_in[3];
  p.Wl    = (const float*)d_in[4];
  p.Wd    = (const float*)d_in[5];
  p.rnn0  = (const float*)d_in[6];
  p.det0  = (const float*)d_in[7];
  p.h0    = (const float*)d_in[8];
  p.pool  = (const float*)d_in[9];
  p.ppls  = (const float*)d_in[10];
  p.pnt   = (const float*)d_in[11];

  char* ws = (char*)d_ws;
  size_t off = 0;
  auto A = [&](size_t nfloats)->void* {
    void* r = ws + off;
    off += ((nfloats*4) + 255) & ~(size_t)255;
    return r;
  };
  p.logits = (float*)A((size_t)NB*VP1R);
  p.lse    = (float*)A(NB);
  p.dlp    = (float*)A(NB*RP1);
  p.rnnT   = (float*)A(ND*NB);
  p.hst    = (float*)A(NB*ND);
  p.hhgT   = (float*)A(ND*NB);
  p.xtT    = (float*)A(ND*NB);
  p.ctxT   = (float*)A(ND*NB);
  p.mask0  = (float*)A(NB*RP1);
  p.mask1  = (float*)A(NB*RP1);
  p.bs0    = (int*)A(NT*NB);
  p.bs1    = (int*)A(NT*NB);
  p.blp0   = (float*)A(NT*NB);
  p.blp1   = (float*)A(NT*NB);
  p.lpsum  = (float*)A(NB);
  p.pkv    = (float*)A(MERGE_N);
  p.pkf    = (unsigned*)A(MERGE_N);
  p.part   = (float*)A((size_t)32*NB*ND);
  p.partL  = (float*)A((size_t)KSPLIT*NB*VP1R);
  p.blkM   = (float*)A(NB*LSE_TILES);
  p.blkS   = (float*)A(NB*LSE_TILES);
  if (off > ws_size) return;

  k0_init<<<64,256,0,stream>>>(p);
  for (int t=0; t<NT; ++t){
    k1_logits<<<dim3(KSPLIT,196),256,0,stream>>>(p.Wl, p.rnnT, p.partL);
    k2a_sum_lse<<<dim3(LSE_TILES,NB),256,0,stream>>>(p.partL, p.logits, p.blkM, p.blkS);
    k2b_lse_det<<<32,512,0,stream>>>(p, t);
    k3_cand<<<dim3(NSLICE,NB),256,0,stream>>>(p, t);
    k4_beam<<<NB,1024,0,stream>>>(p, t);
    k5_rnn<<<128,256,0,stream>>>(p.Wx, p.Wh, p.Wc, p.xtT, p.hhgT, p.ctxT, p.part);
    k6_tanh<<<64,256,0,stream>>>(p);
  }
  k7_out<<<3,256,0,stream>>>(p, (float*)d_out);
}

// Round 7
// 3076.305 us; speedup vs baseline: 1.4082x; 1.1113x over previous
//
#include <hip/hip_runtime.h>
#include <math.h>

#define NB 16
#define NR 100
#define NV 50000
#define ND 1024
#define NT 20
#define VP1 50001
#define VP1R 50004     // padded row stride (float4-aligned rows)
#define VTT 50101
#define RP1 101
#define NEGF (-1e10f)
#define LSE_TILES 49   // ceil(50001/1024)
#define NSLICE 13      // 13*4096 = 53248 >= 50101
#define NBLK3 (NB*NSLICE)      // 208
#define MERGE_N (NBLK3*16)     // 3328
#define KSPLIT 8               // k1 k-groups (128 k each)
#define K5SPLIT 64             // k5 k-groups (16 k each)

struct P {
  const float* embed; const float* Wx; const float* Wh; const float* Wc;
  const float* Wl; const float* Wd; const float* rnn0; const float* det0;
  const float* h0; const float* pool; const float* ppls; const float* pnt;
  float* logits;   // [16][VP1R]
  float* lse;      // [16]
  float* dlp;      // [16][101]
  float* rnnT;     // [1024][16]
  float* hst;      // [16][1024]
  float* hhgT;     // [1024][16]
  float* xtT;      // [1024][16]
  float* ctxT;     // [1024][16]
  float* mask0; float* mask1;       // [16][101] ping-pong
  int* bs0; int* bs1;               // [20][16] ping-pong
  float* blp0; float* blp1;         // [20][16] ping-pong
  float* lpsum;    // [16]
  float* pkv; unsigned* pkf;        // [MERGE_N]
  float* part;     // [K5SPLIT][16][1024] (k5 partials)
  float* partL;    // [KSPLIT][16][VP1R] (k1 partials)
  float* blkM; float* blkS;         // [16*49]
};

__device__ __forceinline__ bool better(float av, unsigned af, float bv, unsigned bf){
  return (av > bv) || (av == bv && af < bf);
}
__device__ __forceinline__ void lsecomb(float& m, float& s, float m2, float s2){
  float M = fmaxf(m, m2);
  if (M == -INFINITY){ m = M; s = 0.f; return; }
  s = s*expf(m - M) + s2*expf(m2 - M);
  m = M;
}

// ---------------- K0: init ----------------
__global__ __launch_bounds__(256) void k0_init(P p){
  int i = blockIdx.x*256 + threadIdx.x;
  int n = gridDim.x*256;
  for (int o=i; o<NB*ND; o+=n){ int b=o>>10, k=o&1023; p.rnnT[k*NB+b] = p.rnn0[o]; }
  for (int o=i; o<NT*NB; o+=n){ p.bs0[o]=0; p.bs1[o]=0; p.blp0[o]=0.f; p.blp1[o]=0.f; }
  for (int o=i; o<NB; o+=n) p.lpsum[o]=0.f;
}

// ---------------- K1: partial logits = rnn_out @ Wl ----------------
// grid (8, 49) x 256 thr. Each thread: 4 columns spaced 256 apart
// (lane-contiguous -> perfectly coalesced scalar loads), 64 accumulators,
// 8-deep double-buffered Wl batches (8 KB in flight per wave).
__global__ __launch_bounds__(256) void k1_logits(const float* __restrict__ Wl,
    const float* __restrict__ rnnT, float* __restrict__ partL){
  __shared__ float rlds[128*16];     // 8 KB: rnnT slice [128 k][16 b]
  int tid = threadIdx.x;
  int g = blockIdx.x;                // k-group 0..7
  int jt = blockIdx.y;               // j-tile 0..48
  int k0 = g*128;
  const float4* r4 = reinterpret_cast<const float4*>(rnnT) + (size_t)k0*4;
  float4* l4 = reinterpret_cast<float4*>(rlds);
  l4[tid] = r4[tid];
  l4[256+tid] = r4[256+tid];
  __syncthreads();
  int j0 = jt*1024 + tid;
  // clamped per-column bases (clamped cols never written)
  const float* wp0 = Wl + ((j0       < VP1) ? j0       : (VP1-1));
  const float* wp1 = Wl + ((j0+256   < VP1) ? j0+256   : (VP1-1));
  const float* wp2 = Wl + ((j0+512   < VP1) ? j0+512   : (VP1-1));
  const float* wp3 = Wl + ((j0+768   < VP1) ? j0+768   : (VP1-1));
  size_t krow = (size_t)k0*VP1;
  float4 acc[16];
  #pragma unroll
  for (int b=0;b<16;++b) acc[b] = make_float4(0.f,0.f,0.f,0.f);
  float4 wa[8], wb[8];
  #define LD8(karr, kb) { \
    _Pragma("unroll") \
    for (int u=0;u<8;++u){ \
      size_t o = krow + (size_t)((kb)+u)*VP1; \
      karr[u].x = wp0[o]; karr[u].y = wp1[o]; \
      karr[u].z = wp2[o]; karr[u].w = wp3[o]; \
    } }
  #define FMA8(karr, kb) { \
    _Pragma("unroll") \
    for (int u=0;u<8;++u){ \
      const float* rr = &rlds[((kb)+u)*16]; \
      float4 wv = karr[u]; \
      _Pragma("unroll") \
      for (int b=0;b<16;++b){ \
        float r = rr[b]; \
        acc[b].x = fmaf(r, wv.x, acc[b].x); \
        acc[b].y = fmaf(r, wv.y, acc[b].y); \
        acc[b].z = fmaf(r, wv.z, acc[b].z); \
        acc[b].w = fmaf(r, wv.w, acc[b].w); \
      } \
    } }
  LD8(wa, 0);
  #pragma unroll 1
  for (int bt=0; bt<8; ++bt){
    LD8(wb, bt*16+8);
    FMA8(wa, bt*16);
    if (bt < 7){ LD8(wa, bt*16+16); }
    FMA8(wb, bt*16+8);
  }
  #undef LD8
  #undef FMA8
  float* pb = partL + (size_t)(g*16)*VP1R;
  bool ok0 = (j0     < VP1), ok1 = (j0+256 < VP1);
  bool ok2 = (j0+512 < VP1), ok3 = (j0+768 < VP1);
  #pragma unroll
  for (int b=0;b<16;++b){
    float* row = pb + (size_t)b*VP1R;
    if (ok0) row[j0]     = acc[b].x;
    if (ok1) row[j0+256] = acc[b].y;
    if (ok2) row[j0+512] = acc[b].z;
    if (ok3) row[j0+768] = acc[b].w;
  }
}

// -------- K2a: sum 8 k-partials -> logits + per-tile online LSE (49 x 16) ----
__global__ __launch_bounds__(256) void k2a_sum_lse(const float* __restrict__ partL,
    float* __restrict__ logits, float* __restrict__ blkM, float* __restrict__ blkS){
  int tile = blockIdx.x, b = blockIdx.y, tid = threadIdx.x;
  int j0 = tile*1024 + tid*4;
  float m = -INFINITY, s = 0.f;
  if (j0 < VP1){
    const float4* base = reinterpret_cast<const float4*>(partL);
    const size_t pstride = VP1R/4;
    size_t jq = (size_t)(j0 >> 2);
    float4 sm4 = make_float4(0.f,0.f,0.f,0.f);
    #pragma unroll
    for (int g=0; g<KSPLIT; ++g){
      float4 a = base[(size_t)(g*16+b)*pstride + jq];
      sm4.x += a.x; sm4.y += a.y; sm4.z += a.z; sm4.w += a.w;
    }
    reinterpret_cast<float4*>(logits)[(size_t)b*pstride + jq] = sm4;
    float vals[4] = {sm4.x, sm4.y, sm4.z, sm4.w};
    #pragma unroll
    for (int e=0;e<4;++e){
      if (j0+e < VP1){
        float x = vals[e];
        if (x > m){ s = s*expf(m-x) + 1.f; m = x; }
        else s += expf(x-m);
      }
    }
  }
  #pragma unroll
  for (int off=32; off; off>>=1){
    float m2 = __shfl_down(m, off), s2 = __shfl_down(s, off);
    lsecomb(m, s, m2, s2);
  }
  __shared__ float wm[4], ws2[4];
  int w = tid >> 6;
  if ((tid & 63) == 0){ wm[w] = m; ws2[w] = s; }
  __syncthreads();
  if (tid == 0){
    float M = wm[0], S = ws2[0];
    lsecomb(M, S, wm[1], ws2[1]);
    lsecomb(M, S, wm[2], ws2[2]);
    lsecomb(M, S, wm[3], ws2[3]);
    blkM[b*LSE_TILES + tile] = M; blkS[b*LSE_TILES + tile] = S;
  }
}

// ---------------- K2b: lse combine (blocks 0-15) + det head (blocks 16-31) ---
__global__ __launch_bounds__(512) void k2b_lse_det(P p, int t){
  int bx = blockIdx.x, tid = threadIdx.x;
  if (bx < 16){
    if (tid < 64){
      int b = bx;
      float m = -INFINITY, s = 0.f;
      if (tid < LSE_TILES){ m = p.blkM[b*LSE_TILES + tid]; s = p.blkS[b*LSE_TILES + tid]; }
      #pragma unroll
      for (int off=32; off; off>>=1){
        float m2 = __shfl_down(m, off), s2 = __shfl_down(s, off);
        lsecomb(m, s, m2, s2);
      }
      if (tid == 0) p.lse[b] = m + logf(s);
    }
    return;
  }
  int b = bx - 16;
  __shared__ float dred[4][129];
  __shared__ float ddet[128];
  int jj = tid & 127, ks = tid >> 7;
  if (t == 0){
    if (tid < 128) ddet[tid] = (tid < RP1) ? p.det0[b*RP1 + tid] : -INFINITY;
    __syncthreads();
  } else {
    float a = 0.f;
    if (jj < RP1){
      const float* hr = p.hst + b*ND;
      for (int k=ks*256; k<ks*256+256; ++k)
        a = fmaf(hr[k], p.Wd[(size_t)k*RP1 + jj], a);
    }
    dred[ks][jj] = a;
    __syncthreads();
    if (tid < 128)
      ddet[tid] = (tid < RP1) ? (dred[0][tid]+dred[1][tid]+dred[2][tid]+dred[3][tid]) : -INFINITY;
    __syncthreads();
  }
  if (tid < 64){
    float a = ddet[tid], a2 = ddet[tid+64];
    float m = fmaxf(a, a2);
    #pragma unroll
    for (int off=32; off; off>>=1) m = fmaxf(m, __shfl_down(m, off));
    m = __shfl(m, 0);
    float e1 = (tid < RP1) ? expf(a - m) : 0.f;
    float e2 = (tid+64 < RP1) ? expf(a2 - m) : 0.f;
    float s = e1 + e2;
    #pragma unroll
    for (int off=32; off; off>>=1) s += __shfl_down(s, off);
    s = __shfl(s, 0);
    float ls = logf(s);
    if (tid < RP1)     p.dlp[b*RP1 + tid]      = a  - m - ls;
    if (tid+64 < RP1)  p.dlp[b*RP1 + tid + 64] = a2 - m - ls;
  }
}

// ------- K3: candidates + per-block top16 (13 slices x 16 beams = 208 blocks) -
__global__ __launch_bounds__(256) void k3_cand(P p, int t){
  int tid = threadIdx.x;
  int slice = blockIdx.x, b = blockIdx.y;
  float lv[16]; unsigned lf[16];
  float cA = p.lpsum[b] - p.lse[b] + p.dlp[b*RP1];
  float cB = p.lpsum[b];
  bool dead = (t==0 && b>0);
  const float* lrow = p.logits + (size_t)b*VP1R;
  const float* drow = p.dlp + b*RP1;
  unsigned fbase = (unsigned)(b*VTT);
  int j0 = slice*4096 + (tid<<2);
  #pragma unroll
  for (int c=0;c<4;++c){
    int j = j0 + c*1024;
    bool vec = (j+4 <= VP1);
    float4 lg = make_float4(0.f,0.f,0.f,0.f);
    if (vec) lg = *reinterpret_cast<const float4*>(lrow + j);
    float le[4] = {lg.x, lg.y, lg.z, lg.w};
    #pragma unroll
    for (int e=0;e<4;++e){
      int jj = j + e;
      float v; unsigned f;
      if (jj < VP1){ v = cA + (vec ? le[e] : lrow[jj]); f = fbase + (unsigned)jj; }
      else if (jj < VTT){ v = cB + drow[jj - NV]; f = fbase + (unsigned)jj; }
      else { v = -3e38f; f = 0xFFFFFFFFu; }
      if (dead && f != 0xFFFFFFFFu) v = NEGF;
      lv[c*4+e] = v; lf[c*4+e] = f;
    }
  }
  __shared__ float wmv[4]; __shared__ unsigned wmf[4];
  __shared__ float sbv; __shared__ unsigned sbf;
  int lane = tid & 63, wid = tid >> 6;
  int blin = b*NSLICE + slice;
  for (int r=0;r<16;++r){
    float bv = lv[0]; unsigned bf = lf[0];
    #pragma unroll
    for (int u=1;u<16;++u) if (better(lv[u],lf[u],bv,bf)){ bv=lv[u]; bf=lf[u]; }
    #pragma unroll
    for (int off=32; off; off>>=1){
      float ov = __shfl_down(bv, off); unsigned of = __shfl_down(bf, off);
      if (better(ov,of,bv,bf)){ bv=ov; bf=of; }
    }
    if (lane==0){ wmv[wid]=bv; wmf[wid]=bf; }
    __syncthreads();
    if (tid==0){
      float mv2=wmv[0]; unsigned mf2=wmf[0];
      #pragma unroll
      for (int w=1;w<4;++w) if (better(wmv[w],wmf[w],mv2,mf2)){ mv2=wmv[w]; mf2=wmf[w]; }
      p.pkv[blin*16+r]=mv2; p.pkf[blin*16+r]=mf2;
      sbv=mv2; sbf=mf2;
    }
    __syncthreads();
    unsigned WF = sbf;
    #pragma unroll
    for (int u=0;u<16;++u) if (lf[u]==WF){ lv[u]=-3e38f; lf[u]=0xFFFFFFFFu; }
  }
}

// ------- K4: redundant global merge + per-beam state + attention (16 x 1024) --
__global__ __launch_bounds__(1024) void k4_beam(P p, int t){
  int bi = blockIdx.x, tid = threadIdx.x;
  float ev[4]; unsigned ef[4];
  #pragma unroll
  for (int c=0;c<4;++c){
    int idx = c*1024 + tid;
    if (idx < MERGE_N){ ev[c]=p.pkv[idx]; ef[c]=p.pkf[idx]; }
    else { ev[c]=-3e38f; ef[c]=0xFFFFFFFFu; }
  }
  __shared__ float wmv[16]; __shared__ unsigned wmf[16];
  __shared__ unsigned sbf;
  __shared__ int wq[16], wc[16]; __shared__ float wvv[16];
  __shared__ float hhs[ND];
  __shared__ float att[128];
  __shared__ float msk[RP1];
  __shared__ int s_q, s_it; __shared__ float s_local;
  int lane = tid & 63, wid = tid >> 6;
  for (int r=0;r<16;++r){
    float bv = ev[0]; unsigned bf = ef[0];
    #pragma unroll
    for (int c=1;c<4;++c) if (better(ev[c],ef[c],bv,bf)){ bv=ev[c]; bf=ef[c]; }
    #pragma unroll
    for (int off=32; off; off>>=1){
      float ov = __shfl_down(bv, off); unsigned of = __shfl_down(bf, off);
      if (better(ov,of,bv,bf)){ bv=ov; bf=of; }
    }
    if (lane==0){ wmv[wid]=bv; wmf[wid]=bf; }
    __syncthreads();
    if (tid==0){
      float mv2=wmv[0]; unsigned mf2=wmf[0];
      #pragma unroll
      for (int w=1;w<16;++w) if (better(wmv[w],wmf[w],mv2,mf2)){ mv2=wmv[w]; mf2=wmf[w]; }
      unsigned q = mf2 / VTT; unsigned c = mf2 - q*VTT;
      wq[r]=(int)q; wc[r]=(int)c; wvv[r]=mv2;
      sbf=mf2;
    }
    __syncthreads();
    unsigned WF = sbf;
    #pragma unroll
    for (int c=0;c<4;++c) if (ef[c]==WF){ ev[c]=-3e38f; ef[c]=0xFFFFFFFFu; }
  }
  if (tid == 0){
    int q = wq[bi], c = wc[bi];
    float local = (c < VP1) ? (p.logits[(size_t)q*VP1R + c] - p.lse[q] + p.dlp[q*RP1])
                            : p.dlp[q*RP1 + (c - NV)];
    int it = (c > NV) ? ((int)p.ppls[((size_t)bi*NR + (c - VP1))*6 + 4] + NV) : c;
    s_q = q; s_it = it; s_local = local;
    p.lpsum[bi] = (c==0) ? -1000.0f : wvv[bi];
  }
  __syncthreads();
  int q = s_q, c = wc[bi], it = s_it;
  const int*   bss = (t&1)? p.bs1 : p.bs0;   int*   bsd = (t&1)? p.bs0 : p.bs1;
  const float* lps = (t&1)? p.blp1: p.blp0;  float* lpd = (t&1)? p.blp0: p.blp1;
  if (tid < t){ bsd[tid*NB+bi] = bss[tid*NB+q]; lpd[tid*NB+bi] = lps[tid*NB+q]; }
  if (tid == t){ bsd[t*NB+bi] = c; lpd[t*NB+bi] = s_local; }
  const float* ms = (t==0) ? p.pnt : ((t&1)? p.mask1 : p.mask0);
  float* md = (t&1)? p.mask0 : p.mask1;
  if (tid < RP1){
    float m = ms[q*RP1 + tid];
    if (tid == 0) m = 0.f;
    if (c > NV && tid == (c - VP1) + 1) m = 1.0f;
    msk[tid] = m; md[bi*RP1 + tid] = m;
  }
  const float* hprev = (t==0) ? p.h0 : p.hst;
  float hv = hprev[(size_t)q*ND + tid];
  hhs[tid] = hv;
  p.hhgT[tid*NB + bi] = hv;
  p.xtT[tid*NB + bi] = p.embed[(size_t)it*ND + tid];
  if (tid >= 100 && tid < 128) att[tid] = -INFINITY;
  __syncthreads();
  int w = tid >> 6, l = tid & 63;
  for (int r=w; r<NR; r+=16){
    const float* pf = p.pool + ((size_t)bi*NR + r)*ND;
    float s = 0.f;
    #pragma unroll
    for (int cc=0;cc<4;++cc){
      float4 pv = *reinterpret_cast<const float4*>(pf + cc*256 + l*4);
      float4 hvv = *reinterpret_cast<const float4*>(&hhs[cc*256 + l*4]);
      s = fmaf(pv.x,hvv.x,s); s = fmaf(pv.y,hvv.y,s);
      s = fmaf(pv.z,hvv.z,s); s = fmaf(pv.w,hvv.w,s);
    }
    #pragma unroll
    for (int off=32; off; off>>=1) s += __shfl_down(s, off);
    if (l == 0) att[r] = (msk[r+1] > 0.f) ? NEGF : s*0.03125f;
  }
  __syncthreads();
  if (tid < 64){
    float a = att[tid], a2 = att[tid+64];
    float m = fmaxf(a, a2);
    #pragma unroll
    for (int off=32; off; off>>=1) m = fmaxf(m, __shfl_down(m, off));
    m = __shfl(m, 0);
    float e1 = expf(a - m);
    float e2 = (tid+64 < 128) ? expf(a2 - m) : 0.f;
    float s = e1 + e2;
    #pragma unroll
    for (int off=32; off; off>>=1) s += __shfl_down(s, off);
    s = __shfl(s, 0);
    att[tid] = e1 / s;
    att[tid+64] = e2 / s;
  }
  __syncthreads();
  float cx = 0.f;
  const float* pb = p.pool + (size_t)bi*NR*ND + tid;
  #pragma unroll 4
  for (int r=0;r<NR;++r) cx = fmaf(att[r], pb[(size_t)r*ND], cx);
  p.ctxT[tid*NB + bi] = cx;
}

// ------ K5: fused 3-matrix RNN GEMM partials (256 blocks = 4 jb x 64 ks) -----
__global__ __launch_bounds__(256) void k5_rnn(const float* __restrict__ Wx,
    const float* __restrict__ Wh, const float* __restrict__ Wc,
    const float* __restrict__ xtT, const float* __restrict__ hhgT,
    const float* __restrict__ ctxT, float* __restrict__ part){
  int tid = threadIdx.x;
  int jb = blockIdx.x & 3, ks = blockIdx.x >> 2;
  int j = jb*256 + tid;
  int k0 = ks*16;
  float acc[16];
  #pragma unroll
  for (int b=0;b<16;++b) acc[b]=0.f;
  for (int k=k0;k<k0+16;++k){
    float wx = Wx[(size_t)k*ND + j];
    float wh = Wh[(size_t)k*ND + j];
    float wc = Wc[(size_t)k*ND + j];
    const float4* xv = reinterpret_cast<const float4*>(xtT)  + (size_t)k*4;
    const float4* hv = reinterpret_cast<const float4*>(hhgT) + (size_t)k*4;
    const float4* cv = reinterpret_cast<const float4*>(ctxT) + (size_t)k*4;
    float4 x0=xv[0],x1=xv[1],x2=xv[2],x3=xv[3];
    float4 h0=hv[0],h1=hv[1],h2=hv[2],h3=hv[3];
    float4 c0=cv[0],c1=cv[1],c2=cv[2],c3=cv[3];
    acc[0]=fmaf(x0.x,wx,fmaf(h0.x,wh,fmaf(c0.x,wc,acc[0])));
    acc[1]=fmaf(x0.y,wx,fmaf(h0.y,wh,fmaf(c0.y,wc,acc[1])));
    acc[2]=fmaf(x0.z,wx,fmaf(h0.z,wh,fmaf(c0.z,wc,acc[2])));
    acc[3]=fmaf(x0.w,wx,fmaf(h0.w,wh,fmaf(c0.w,wc,acc[3])));
    acc[4]=fmaf(x1.x,wx,fmaf(h1.x,wh,fmaf(c1.x,wc,acc[4])));
    acc[5]=fmaf(x1.y,wx,fmaf(h1.y,wh,fmaf(c1.y,wc,acc[5])));
    acc[6]=fmaf(x1.z,wx,fmaf(h1.z,wh,fmaf(c1.z,wc,acc[6])));
    acc[7]=fmaf(x1.w,wx,fmaf(h1.w,wh,fmaf(c1.w,wc,acc[7])));
    acc[8]=fmaf(x2.x,wx,fmaf(h2.x,wh,fmaf(c2.x,wc,acc[8])));
    acc[9]=fmaf(x2.y,wx,fmaf(h2.y,wh,fmaf(c2.y,wc,acc[9])));
    acc[10]=fmaf(x2.z,wx,fmaf(h2.z,wh,fmaf(c2.z,wc,acc[10])));
    acc[11]=fmaf(x2.w,wx,fmaf(h2.w,wh,fmaf(c2.w,wc,acc[11])));
    acc[12]=fmaf(x3.x,wx,fmaf(h3.x,wh,fmaf(c3.x,wc,acc[12])));
    acc[13]=fmaf(x3.y,wx,fmaf(h3.y,wh,fmaf(c3.y,wc,acc[13])));
    acc[14]=fmaf(x3.z,wx,fmaf(h3.z,wh,fmaf(c3.z,wc,acc[14])));
    acc[15]=fmaf(x3.w,wx,fmaf(h3.w,wh,fmaf(c3.w,wc,acc[15])));
  }
  #pragma unroll
  for (int b=0;b<16;++b) part[((size_t)ks*16 + b)*ND + j] = acc[b];
}

// ---------------- K6: reduce 64 partials + tanh -> h_new ----------------
__global__ __launch_bounds__(256) void k6_tanh(P p){
  int o = blockIdx.x*256 + threadIdx.x;
  int b = o >> 10, j = o & 1023;
  float s = 0.f;
  for (int ks=0; ks<K5SPLIT; ++ks) s += p.part[((size_t)ks*16 + b)*ND + j];
  float hv = tanhf(s);
  p.hst[o] = hv;
  p.rnnT[j*NB + b] = hv;
}

// ---------------- K7: pack outputs (f32) ----------------
__global__ __launch_bounds__(256) void k7_out(P p, float* out){
  int i = blockIdx.x*256 + threadIdx.x;
  if (i < NT*NB)            out[i] = (float)p.bs0[i];
  else if (i < 2*NT*NB)     out[i] = p.blp0[i - NT*NB];
  else if (i < 2*NT*NB+NB)  out[i] = p.lpsum[i - 2*NT*NB];
}

// ---------------- host ----------------
extern "C" void kernel_launch(void* const* d_in, const int* in_sizes, int n_in,
                              void* d_out, int out_size, void* d_ws, size_t ws_size,
                              hipStream_t stream) {
  P p;
  p.embed = (const float*)d_in[0];
  p.Wx    = (const float*)d_in[1];
  p.Wh    = (const float*)d_in[2];
  p.Wc    = (const float*)d_in[3];
  p.Wl    = (const float*)d_in[4];
  p.Wd    = (const float*)d_in[5];
  p.rnn0  = (const float*)d_in[6];
  p.det0  = (const float*)d_in[7];
  p.h0    = (const float*)d_in[8];
  p.pool  = (const float*)d_in[9];
  p.ppls  = (const float*)d_in[10];
  p.pnt   = (const float*)d_in[11];

  char* ws = (char*)d_ws;
  size_t off = 0;
  auto A = [&](size_t nfloats)->void* {
    void* r = ws + off;
    off += ((nfloats*4) + 255) & ~(size_t)255;
    return r;
  };
  p.logits = (float*)A((size_t)NB*VP1R);
  p.lse    = (float*)A(NB);
  p.dlp    = (float*)A(NB*RP1);
  p.rnnT   = (float*)A(ND*NB);
  p.hst    = (float*)A(NB*ND);
  p.hhgT   = (float*)A(ND*NB);
  p.xtT    = (float*)A(ND*NB);
  p.ctxT   = (float*)A(ND*NB);
  p.mask0  = (float*)A(NB*RP1);
  p.mask1  = (float*)A(NB*RP1);
  p.bs0    = (int*)A(NT*NB);
  p.bs1    = (int*)A(NT*NB);
  p.blp0   = (float*)A(NT*NB);
  p.blp1   = (float*)A(NT*NB);
  p.lpsum  = (float*)A(NB);
  p.pkv    = (float*)A(MERGE_N);
  p.pkf    = (unsigned*)A(MERGE_N);
  p.part   = (float*)A((size_t)K5SPLIT*NB*ND);
  p.partL  = (float*)A((size_t)KSPLIT*NB*VP1R);
  p.blkM   = (float*)A(NB*LSE_TILES);
  p.blkS   = (float*)A(NB*LSE_TILES);
  if (off > ws_size) return;

  k0_init<<<64,256,0,stream>>>(p);
  for (int t=0; t<NT; ++t){
    k1_logits<<<dim3(KSPLIT,49),256,0,stream>>>(p.Wl, p.rnnT, p.partL);
    k2a_sum_lse<<<dim3(LSE_TILES,NB),256,0,stream>>>(p.partL, p.logits, p.blkM, p.blkS);
    k2b_lse_det<<<32,512,0,stream>>>(p, t);
    k3_cand<<<dim3(NSLICE,NB),256,0,stream>>>(p, t);
    k4_beam<<<NB,1024,0,stream>>>(p, t);
    k5_rnn<<<256,256,0,stream>>>(p.Wx, p.Wh, p.Wc, p.xtT, p.hhgT, p.ctxT, p.part);
    k6_tanh<<<64,256,0,stream>>>(p);
  }
  k7_out<<<3,256,0,stream>>>(p, (float*)d_out);
}